// Round 9
// baseline (411.103 us; speedup 1.0000x reference)
//
#include <hip/hip_runtime.h>
#include <hip/hip_bf16.h>

typedef short bf16x8 __attribute__((ext_vector_type(8)));
typedef float f32x4 __attribute__((ext_vector_type(4)));
typedef __attribute__((address_space(1))) const void gconst_t;
typedef __attribute__((address_space(3))) void lds_t;

#define DEVI __device__ __forceinline__

constexpr int BATCH   = 8192;
constexpr int IN_DIM  = 1024;
constexpr int HID     = 4096;
constexpr int OUT_DIM = 1024;
constexpr int NE      = 3;

// ---- workspace layout (bytes) ----
constexpr size_t XBF_OFF  = 0;                         // x bf16 (hi): 16 MB
constexpr size_t W1T_OFF  = 16777216;                  // W1T bf16 [E][HID][IN]: 24 MB
constexpr size_t W2T_OFF  = W1T_OFF + 25165824;        // W2T bf16 [E][OUT][HID]: 24 MB
constexpr size_t H_OFF    = W2T_OFF + 25165824;        // H bf16 grouped rows: 64 MB
constexpr size_t XLO_OFF  = H_OFF;                     // x_lo aliases H[0,16MB)
constexpr size_t RHP_OFF  = H_OFF + 16777216;          // rhpart f32 [3][8192][128] = 12.6 MB
                                                       // aliases H[16MB,29MB) — both dead
                                                       // before gemm0 writes H
constexpr size_t META_OFF = H_OFF + 67108864;          // counts[16], toklist[3*8192]
constexpr size_t W3_OFF   = META_OFF + 131072;         // router B [128][3072] bf16: 768 KB

DEVI unsigned short f2bf(float f) {
  __hip_bfloat16 h = __float2bfloat16(f);
  return *reinterpret_cast<unsigned short*>(&h);
}
DEVI float bf2f(unsigned short u) {
  unsigned v = (unsigned)u << 16;
  return __uint_as_float(v);
}

// 128-B-row swizzle (round-2-verified conflict-free): XOR bits 4-6 with row&7.
// Bits >=7 untouched -> row = byte>>7 is swizzle-invariant.
DEVI unsigned swz(unsigned b) { return b ^ (((b >> 7) & 7u) << 4); }

// =====================================================================
// prepA: split-bf16 inputs for the MFMA router (+ xb for gemm0).
//   [0,512)    x -> xb (hi) + xlo:  lo = bf16(x - f32(hi))
//   [512,544)  rw1 [1024][128] -> w3 [128][3072] = [w_hi | w_hi | w_lo]
// =====================================================================
__global__ __launch_bounds__(256) void prepA_kernel(
    const float* __restrict__ x, const float* __restrict__ rw1,
    unsigned short* __restrict__ xb, unsigned short* __restrict__ xlo,
    unsigned short* __restrict__ w3) {
  __shared__ float tile[64][65];
  const int b = blockIdx.x;
  const int tid = threadIdx.x;
  if (b < 512) {
    const float4* xv4 = (const float4*)x;
    const int total = BATCH * IN_DIM / 4;
    for (int i = b * 256 + tid; i < total; i += 512 * 256) {
      const float4 v = xv4[i];
      ushort4 h, l;
      h.x = f2bf(v.x); l.x = f2bf(v.x - bf2f(h.x));
      h.y = f2bf(v.y); l.y = f2bf(v.y - bf2f(h.y));
      h.z = f2bf(v.z); l.z = f2bf(v.z - bf2f(h.z));
      h.w = f2bf(v.w); l.w = f2bf(v.w - bf2f(h.w));
      ((ushort4*)xb)[i] = h;
      ((ushort4*)xlo)[i] = l;
    }
  } else {
    const int w = b - 512;            // 0..31
    const int r0 = (w >> 1) * 64;     // k-tile base
    const int c0 = (w & 1) * 64;      // h-tile base
    const int tr = tid >> 4;
    const int tc = (tid & 15) << 2;
#pragma unroll
    for (int i = 0; i < 4; i++) {
      const int r = tr + i * 16;
      const float4 v = *(const float4*)(rw1 + (size_t)(r0 + r) * 128 + (c0 + tc));
      tile[r][tc + 0] = v.x; tile[r][tc + 1] = v.y; tile[r][tc + 2] = v.z; tile[r][tc + 3] = v.w;
    }
    __syncthreads();
#pragma unroll
    for (int i = 0; i < 4; i++) {
      const int c = tr + i * 16;      // h-local
      ushort4 hi, lo;
      {
        float f;
        f = tile[tc + 0][c]; hi.x = f2bf(f); lo.x = f2bf(f - bf2f(hi.x));
        f = tile[tc + 1][c]; hi.y = f2bf(f); lo.y = f2bf(f - bf2f(hi.y));
        f = tile[tc + 2][c]; hi.z = f2bf(f); lo.z = f2bf(f - bf2f(hi.z));
        f = tile[tc + 3][c]; hi.w = f2bf(f); lo.w = f2bf(f - bf2f(hi.w));
      }
      unsigned short* base = w3 + (size_t)(c0 + c) * 3072 + (r0 + tc);
      *(ushort4*)(base)        = hi;
      *(ushort4*)(base + 1024) = hi;
      *(ushort4*)(base + 2048) = lo;
    }
  }
}

// =====================================================================
// Router pass 1: 3 segment GEMMs (hi@hi, lo@hi, hi@lo), each 8192x128xK=1024,
// m97 structure (128x128 tile, BK=64, 4 waves, single 32 KB LDS buffer,
// 2 syncthreads per K-step, compiler-scheduled waits). grid (64, 3).
// Writes rhpart[seg][tok][128] f32 (summed deterministically in pass 2).
// =====================================================================
__global__ __launch_bounds__(256) void router_part(
    const unsigned short* __restrict__ xhi, const unsigned short* __restrict__ xlo,
    const unsigned short* __restrict__ w3, float* __restrict__ rhpart) {
  __shared__ unsigned short At[128 * 64];   // 16 KB
  __shared__ unsigned short Bt[128 * 64];   // 16 KB
  const int tid = threadIdx.x;
  const int m0 = blockIdx.x * 128;
  const int seg = blockIdx.y;               // 0,1,2
  const unsigned short* Abase = (seg == 1) ? xlo : xhi;
  const int kcol0 = seg * 1024;             // w3 column base

  const unsigned short* asrc[4];
  const unsigned short* bsrc[4];
  unsigned loff[4];
#pragma unroll
  for (int l = 0; l < 4; l++) {
    const unsigned o = l * 4096u + (unsigned)tid * 16u;
    const unsigned p = swz(o);
    const int row = (int)(o >> 7);            // 0..127 (swizzle-invariant)
    const int kel = (int)((p & 127u) >> 1);   // 0..63
    loff[l] = o;
    asrc[l] = Abase + (size_t)(m0 + row) * 1024 + kel;
    bsrc[l] = w3 + (size_t)row * 3072 + kcol0 + kel;
  }

  f32x4 acc[4][4];
#pragma unroll
  for (int i = 0; i < 4; i++)
#pragma unroll
    for (int j = 0; j < 4; j++) acc[i][j] = {0.f, 0.f, 0.f, 0.f};

  const int lane = tid & 63;
  const int wave = tid >> 6;
  const int wm = (wave >> 1) * 64;
  const int wn = (wave & 1) * 64;
  const int fr = lane & 15;
  const int fc = lane >> 4;

  for (int t = 0; t < 16; ++t) {
    __syncthreads();                       // WAR: prior step's reads done
#pragma unroll
    for (int l = 0; l < 4; l++) {
      __builtin_amdgcn_global_load_lds((gconst_t*)(asrc[l] + t * 64),
                                       (lds_t*)((char*)At + loff[l]), 16, 0, 0);
      __builtin_amdgcn_global_load_lds((gconst_t*)(bsrc[l] + t * 64),
                                       (lds_t*)((char*)Bt + loff[l]), 16, 0, 0);
    }
    __syncthreads();                       // RAW: compiler drains vmcnt here
    bf16x8 af[2][4], bv[2][4];
#pragma unroll
    for (int ks = 0; ks < 2; ks++) {
#pragma unroll
      for (int m = 0; m < 4; m++) {
        const unsigned L = (unsigned)(wm + m * 16 + fr) * 128u + (unsigned)(ks * 64 + fc * 16);
        af[ks][m] = *(const bf16x8*)((const char*)At + swz(L));
      }
#pragma unroll
      for (int n = 0; n < 4; n++) {
        const unsigned L = (unsigned)(wn + n * 16 + fr) * 128u + (unsigned)(ks * 64 + fc * 16);
        bv[ks][n] = *(const bf16x8*)((const char*)Bt + swz(L));
      }
    }
#pragma unroll
    for (int ks = 0; ks < 2; ks++)
#pragma unroll
      for (int m = 0; m < 4; m++)
#pragma unroll
        for (int n = 0; n < 4; n++)
          acc[m][n] = __builtin_amdgcn_mfma_f32_16x16x32_bf16(af[ks][m], bv[ks][n], acc[m][n], 0, 0, 0);
  }

  // write partials: C/D layout col=lane&15, row=(lane>>4)*4+reg
  const int crow = (lane >> 4) * 4;
  const int ccol = lane & 15;
  float* outp = rhpart + (size_t)seg * BATCH * 128;
#pragma unroll
  for (int mi = 0; mi < 4; mi++) {
#pragma unroll
    for (int r = 0; r < 4; r++) {
      const int tok = m0 + wm + mi * 16 + crow + r;
#pragma unroll
      for (int ni = 0; ni < 4; ni++)
        outp[(size_t)tok * 128 + (wn + ni * 16 + ccol)] = acc[mi][ni][r];
    }
  }
}

// =====================================================================
// Router pass 2: rh = relu(sum of 3 partials + b1); logits = rh@rw2 + b2
// (j ascending); argmax; atomic bucket. 64 blocks x 128 tokens.
// Deterministic (fixed summation order, no float atomics).
// =====================================================================
__global__ __launch_bounds__(256) void router_finish(
    const float* __restrict__ rhpart, const float* __restrict__ rb1,
    const float* __restrict__ rw2, const float* __restrict__ rb2,
    int* __restrict__ counts, int* __restrict__ toklist) {
  __shared__ float rh[128 * 132];
  __shared__ float lg[128 * 3];
  const int tid = threadIdx.x;
  const int t0 = blockIdx.x * 128;
  constexpr size_t SEG = (size_t)BATCH * 128;

  for (int i = tid; i < 128 * 32; i += 256) {
    const int tok = i >> 5;
    const int c4 = (i & 31) * 4;
    const size_t base = (size_t)(t0 + tok) * 128 + c4;
    const float4 a = *(const float4*)(rhpart + base);
    const float4 b = *(const float4*)(rhpart + SEG + base);
    const float4 c = *(const float4*)(rhpart + 2 * SEG + base);
    const float4 bb = *(const float4*)(rb1 + c4);
    rh[tok * 132 + c4 + 0] = fmaxf(a.x + b.x + c.x + bb.x, 0.f);
    rh[tok * 132 + c4 + 1] = fmaxf(a.y + b.y + c.y + bb.y, 0.f);
    rh[tok * 132 + c4 + 2] = fmaxf(a.z + b.z + c.z + bb.z, 0.f);
    rh[tok * 132 + c4 + 3] = fmaxf(a.w + b.w + c.w + bb.w, 0.f);
  }
  __syncthreads();
#pragma unroll
  for (int pass = 0; pass < 2; ++pass) {
    const int t = tid + pass * 256;
    if (t < 384) {
      const int tok = t / 3, e = t - tok * 3;
      float s = rb2[e];
#pragma unroll 4
      for (int j = 0; j < 128; ++j) s = fmaf(rh[tok * 132 + j], rw2[j * 3 + e], s);
      lg[tok * 3 + e] = s;
    }
  }
  __syncthreads();
  if (tid < 128) {
    const float l0 = lg[tid * 3], l1 = lg[tid * 3 + 1], l2 = lg[tid * 3 + 2];
    int sel = 0; float m = l0;
    if (l1 > m) { m = l1; sel = 1; }
    if (l2 > m) { m = l2; sel = 2; }
    const int slot = atomicAdd(&counts[sel], 1);
    toklist[sel * BATCH + slot] = t0 + tid;
  }
}

// =====================================================================
// prep2: weight transpose+cvt only.
// =====================================================================
__global__ __launch_bounds__(256) void prep2_kernel(
    const float* __restrict__ ew1, const float* __restrict__ ew2,
    unsigned short* __restrict__ w1t, unsigned short* __restrict__ w2t) {
  __shared__ float tile[64][65];
  const int b = blockIdx.x;
  const int tid = threadIdx.x;

  const float* src; unsigned short* dst; int R, C, r0, c0;
  if (b < 3072) {
    const int e = b / 1024, w = b % 1024;
    src = ew1 + (size_t)e * 1024 * 4096; dst = w1t + (size_t)e * 4096 * 1024;
    R = 1024; C = 4096; r0 = (w & 15) * 64; c0 = (w >> 4) * 64;
  } else {
    const int bb = b - 3072, e = bb / 1024, w = bb % 1024;
    src = ew2 + (size_t)e * 4096 * 1024; dst = w2t + (size_t)e * 1024 * 4096;
    R = 4096; C = 1024; r0 = (w & 63) * 64; c0 = (w >> 6) * 64;
  }
  const int tr = tid >> 4;
  const int tc = (tid & 15) << 2;
#pragma unroll
  for (int i = 0; i < 4; i++) {
    const int r = tr + i * 16;
    const float4 v = *(const float4*)(src + (size_t)(r0 + r) * C + (c0 + tc));
    tile[r][tc + 0] = v.x; tile[r][tc + 1] = v.y; tile[r][tc + 2] = v.z; tile[r][tc + 3] = v.w;
  }
  __syncthreads();
#pragma unroll
  for (int i = 0; i < 4; i++) {
    const int c = tr + i * 16;
    ushort4 o;
    o.x = f2bf(tile[tc + 0][c]);
    o.y = f2bf(tile[tc + 1][c]);
    o.z = f2bf(tile[tc + 2][c]);
    o.w = f2bf(tile[tc + 3][c]);
    *(ushort4*)(dst + (size_t)(c0 + c) * R + (r0 + tc)) = o;
  }
}

// =====================================================================
// Grouped bf16 GEMM, m97 structure: 128x128 tile, BK=64, 4 waves (2x2,
// 64x64/wave), SINGLE 32 KB LDS buffer, 2 syncthreads per K-step, no
// manual waitcnt (compiler drains vmcnt before barrier, fine-grained
// lgkmcnt between ds_read and MFMA). ~3 blocks/CU -> cross-block overlap
// hides the drain (m114). Proven 874-912 TF on dense 4096^3.
// MODE 0: K=1024, A = xb gathered via toklist, relu(+b1) -> H bf16 grouped.
// MODE 1: K=4096, A = H grouped, +b2 -> scatter f32 rows of d_out.
// =====================================================================
template <int MODE>
__global__ __launch_bounds__(256) void moe_gemm(
    const unsigned short* __restrict__ Abase, const unsigned short* __restrict__ Ball,
    const float* __restrict__ biasAll, unsigned short* __restrict__ Hout,
    float* __restrict__ Yout, const int* __restrict__ toklist, const int* __restrict__ counts,
    float* __restrict__ tail) {
  constexpr int N  = (MODE == 0) ? HID : OUT_DIM;
  constexpr int K  = (MODE == 0) ? IN_DIM : HID;
  constexpr int NT = K / 64;

  const int tid = threadIdx.x;
  if (MODE == 0 && blockIdx.x == 0 && blockIdx.y == 0 && tid < NE)
    tail[tid] = (float)counts[tid];

  const int c0 = counts[0], c1 = counts[1], c2 = counts[2];
  const int mb0 = (c0 + 127) >> 7, mb1 = (c1 + 127) >> 7, mb2 = (c2 + 127) >> 7;
  const int bx = blockIdx.x;
  int e, mblk;
  if (bx < mb0) { e = 0; mblk = bx; }
  else if (bx < mb0 + mb1) { e = 1; mblk = bx - mb0; }
  else if (bx < mb0 + mb1 + mb2) { e = 2; mblk = bx - mb0 - mb1; }
  else return;
  const int cnt = (e == 0) ? c0 : (e == 1) ? c1 : c2;
  const int m0 = mblk * 128;
  const int n0 = blockIdx.y * 128;
  const int off_e = (e > 0 ? c0 : 0) + (e > 1 ? c1 : 0);
  const unsigned short* Bmat = Ball + (size_t)e * ((size_t)N * K);
  const float* bias = biasAll + (size_t)e * N;

  __shared__ unsigned short At[128 * 64];   // 16 KB
  __shared__ unsigned short Bt[128 * 64];   // 16 KB

  // staging: LDS dest linear o; global source pre-swizzled (kel from p);
  // row = o>>7 is swizzle-invariant for 128-B rows.
  const unsigned short* asrc[4];
  const unsigned short* bsrc[4];
  unsigned loff[4];
#pragma unroll
  for (int l = 0; l < 4; l++) {
    const unsigned o = l * 4096u + (unsigned)tid * 16u;
    const unsigned p = swz(o);
    const int row = (int)(o >> 7);            // 0..127
    const int kel = (int)((p & 127u) >> 1);   // 0..63
    loff[l] = o;
    int slot = m0 + row; if (slot > cnt - 1) slot = cnt - 1;
    const size_t arow = (MODE == 0) ? (size_t)toklist[e * BATCH + slot]
                                    : (size_t)(off_e + slot);
    asrc[l] = Abase + arow * K + kel;
    bsrc[l] = Bmat + (size_t)(n0 + row) * K + kel;
  }

  f32x4 acc[4][4];
#pragma unroll
  for (int i = 0; i < 4; i++)
#pragma unroll
    for (int j = 0; j < 4; j++) acc[i][j] = {0.f, 0.f, 0.f, 0.f};

  const int lane = tid & 63;
  const int wave = tid >> 6;
  const int wm = (wave >> 1) * 64;
  const int wn = (wave & 1) * 64;
  const int fr = lane & 15;
  const int fc = lane >> 4;

  for (int t = 0; t < NT; ++t) {
    __syncthreads();                       // WAR: prior step's reads done
#pragma unroll
    for (int l = 0; l < 4; l++) {
      __builtin_amdgcn_global_load_lds((gconst_t*)(asrc[l] + t * 64),
                                       (lds_t*)((char*)At + loff[l]), 16, 0, 0);
      __builtin_amdgcn_global_load_lds((gconst_t*)(bsrc[l] + t * 64),
                                       (lds_t*)((char*)Bt + loff[l]), 16, 0, 0);
    }
    __syncthreads();                       // RAW: compiler drains vmcnt here
    bf16x8 af[2][4], bv[2][4];
#pragma unroll
    for (int ks = 0; ks < 2; ks++) {
#pragma unroll
      for (int m = 0; m < 4; m++) {
        const unsigned L = (unsigned)(wm + m * 16 + fr) * 128u + (unsigned)(ks * 64 + fc * 16);
        af[ks][m] = *(const bf16x8*)((const char*)At + swz(L));
      }
#pragma unroll
      for (int n = 0; n < 4; n++) {
        const unsigned L = (unsigned)(wn + n * 16 + fr) * 128u + (unsigned)(ks * 64 + fc * 16);
        bv[ks][n] = *(const bf16x8*)((const char*)Bt + swz(L));
      }
    }
#pragma unroll
    for (int ks = 0; ks < 2; ks++)
#pragma unroll
      for (int m = 0; m < 4; m++)
#pragma unroll
        for (int n = 0; n < 4; n++)
          acc[m][n] = __builtin_amdgcn_mfma_f32_16x16x32_bf16(af[ks][m], bv[ks][n], acc[m][n], 0, 0, 0);
  }

  // epilogue: C/D layout col=lane&15, row=(lane>>4)*4+reg  [HW-verified m89/m91]
  const int crow = (lane >> 4) * 4;
  const int ccol = lane & 15;
#pragma unroll
  for (int mi = 0; mi < 4; mi++) {
#pragma unroll
    for (int r = 0; r < 4; r++) {
      const int slot = m0 + wm + mi * 16 + crow + r;
      if (slot >= cnt) continue;
      if (MODE == 0) {
        unsigned short* hrow = Hout + (size_t)(off_e + slot) * HID;
#pragma unroll
        for (int ni = 0; ni < 4; ni++) {
          const int n = n0 + wn + ni * 16 + ccol;
          const float v = acc[mi][ni][r] + bias[n];
          hrow[n] = f2bf(fmaxf(v, 0.f));
        }
      } else {
        const int tok = toklist[e * BATCH + slot];
        float* yrow = Yout + (size_t)tok * OUT_DIM;
#pragma unroll
        for (int ni = 0; ni < 4; ni++) {
          const int n = n0 + wn + ni * 16 + ccol;
          yrow[n] = acc[mi][ni][r] + bias[n];
        }
      }
    }
  }
}

extern "C" void kernel_launch(void* const* d_in, const int* in_sizes, int n_in,
                              void* d_out, int out_size, void* d_ws, size_t ws_size,
                              hipStream_t stream) {
  const float* x   = (const float*)d_in[0];
  const float* rw1 = (const float*)d_in[1];
  const float* rb1 = (const float*)d_in[2];
  const float* rw2 = (const float*)d_in[3];
  const float* rb2 = (const float*)d_in[4];
  const float* ew1 = (const float*)d_in[5];
  const float* eb1 = (const float*)d_in[6];
  const float* ew2 = (const float*)d_in[7];
  const float* eb2 = (const float*)d_in[8];
  float* out = (float*)d_out;

  char* ws = (char*)d_ws;
  unsigned short* xb  = (unsigned short*)(ws + XBF_OFF);
  unsigned short* w1t = (unsigned short*)(ws + W1T_OFF);
  unsigned short* w2t = (unsigned short*)(ws + W2T_OFF);
  unsigned short* h   = (unsigned short*)(ws + H_OFF);
  unsigned short* xlo = (unsigned short*)(ws + XLO_OFF);   // aliases H (see layout)
  float* rhpart = (float*)(ws + RHP_OFF);                  // aliases H (see layout)
  int* counts  = (int*)(ws + META_OFF);
  int* toklist = counts + 16;
  unsigned short* w3 = (unsigned short*)(ws + W3_OFF);
  float* tail = out + (size_t)BATCH * OUT_DIM;

  hipMemsetAsync(counts, 0, 64, stream);
  prepA_kernel<<<544, 256, 0, stream>>>(x, rw1, xb, xlo, w3);
  router_part<<<dim3(64, 3), 256, 0, stream>>>(xb, xlo, w3, rhpart);
  router_finish<<<64, 256, 0, stream>>>(rhpart, rb1, rw2, rb2, counts, toklist);
  prep2_kernel<<<6144, 256, 0, stream>>>(ew1, ew2, w1t, w2t);
  moe_gemm<0><<<dim3(66, 32), 256, 0, stream>>>(xb, w1t, eb1, h, nullptr, toklist, counts, tail);
  moe_gemm<1><<<dim3(66, 8), 256, 0, stream>>>(h, w2t, eb2, nullptr, out, toklist, counts, tail);
}

// Round 10
// 364.013 us; speedup vs baseline: 1.1294x; 1.1294x over previous
//
#include <hip/hip_runtime.h>
#include <hip/hip_bf16.h>

typedef short bf16x8 __attribute__((ext_vector_type(8)));
typedef float f32x4 __attribute__((ext_vector_type(4)));
typedef __attribute__((address_space(1))) const void gconst_t;
typedef __attribute__((address_space(3))) void lds_t;

#define DEVI __device__ __forceinline__

constexpr int BATCH   = 8192;
constexpr int IN_DIM  = 1024;
constexpr int HID     = 4096;
constexpr int OUT_DIM = 1024;
constexpr int NE      = 3;

// ---- workspace layout (bytes) ----
constexpr size_t XBF_OFF  = 0;                         // x bf16 (hi): 16 MB
constexpr size_t W1T_OFF  = 16777216;                  // W1T bf16 [E][HID][IN]: 24 MB
constexpr size_t W2T_OFF  = W1T_OFF + 25165824;        // W2T bf16 [E][OUT][HID]: 24 MB
constexpr size_t H_OFF    = W2T_OFF + 25165824;        // H bf16 grouped rows: 64 MB
constexpr size_t XLO_OFF  = H_OFF;                     // x_lo aliases H[0,16MB)
constexpr size_t RHP_OFF  = H_OFF + 16777216;          // rhpart f32 [3][8192][128] = 12.6 MB
                                                       // aliases H[16MB,29MB) — both dead
                                                       // before gemm0 writes H
constexpr size_t META_OFF = H_OFF + 67108864;          // counts[16], toklist[3*8192]
constexpr size_t W3_OFF   = META_OFF + 131072;         // router B [128][3072] bf16: 768 KB

DEVI unsigned short f2bf(float f) {
  __hip_bfloat16 h = __float2bfloat16(f);
  return *reinterpret_cast<unsigned short*>(&h);
}
DEVI float bf2f(unsigned short u) {
  unsigned v = (unsigned)u << 16;
  return __uint_as_float(v);
}

// 128-B-row swizzle (router_part only): XOR bits 4-6 with row&7.
DEVI unsigned swz(unsigned b) { return b ^ (((b >> 7) & 7u) << 4); }

// =====================================================================
// prepA: split-bf16 inputs for the MFMA router (+ xb for gemm0).
//   [0,512)    x -> xb (hi) + xlo:  lo = bf16(x - f32(hi))
//   [512,544)  rw1 [1024][128] -> w3 [128][3072] = [w_hi | w_hi | w_lo]
// =====================================================================
__global__ __launch_bounds__(256) void prepA_kernel(
    const float* __restrict__ x, const float* __restrict__ rw1,
    unsigned short* __restrict__ xb, unsigned short* __restrict__ xlo,
    unsigned short* __restrict__ w3) {
  __shared__ float tile[64][65];
  const int b = blockIdx.x;
  const int tid = threadIdx.x;
  if (b < 512) {
    const float4* xv4 = (const float4*)x;
    const int total = BATCH * IN_DIM / 4;
    for (int i = b * 256 + tid; i < total; i += 512 * 256) {
      const float4 v = xv4[i];
      ushort4 h, l;
      h.x = f2bf(v.x); l.x = f2bf(v.x - bf2f(h.x));
      h.y = f2bf(v.y); l.y = f2bf(v.y - bf2f(h.y));
      h.z = f2bf(v.z); l.z = f2bf(v.z - bf2f(h.z));
      h.w = f2bf(v.w); l.w = f2bf(v.w - bf2f(h.w));
      ((ushort4*)xb)[i] = h;
      ((ushort4*)xlo)[i] = l;
    }
  } else {
    const int w = b - 512;            // 0..31
    const int r0 = (w >> 1) * 64;     // k-tile base
    const int c0 = (w & 1) * 64;      // h-tile base
    const int tr = tid >> 4;
    const int tc = (tid & 15) << 2;
#pragma unroll
    for (int i = 0; i < 4; i++) {
      const int r = tr + i * 16;
      const float4 v = *(const float4*)(rw1 + (size_t)(r0 + r) * 128 + (c0 + tc));
      tile[r][tc + 0] = v.x; tile[r][tc + 1] = v.y; tile[r][tc + 2] = v.z; tile[r][tc + 3] = v.w;
    }
    __syncthreads();
#pragma unroll
    for (int i = 0; i < 4; i++) {
      const int c = tr + i * 16;      // h-local
      ushort4 hi, lo;
      {
        float f;
        f = tile[tc + 0][c]; hi.x = f2bf(f); lo.x = f2bf(f - bf2f(hi.x));
        f = tile[tc + 1][c]; hi.y = f2bf(f); lo.y = f2bf(f - bf2f(hi.y));
        f = tile[tc + 2][c]; hi.z = f2bf(f); lo.z = f2bf(f - bf2f(hi.z));
        f = tile[tc + 3][c]; hi.w = f2bf(f); lo.w = f2bf(f - bf2f(hi.w));
      }
      unsigned short* base = w3 + (size_t)(c0 + c) * 3072 + (r0 + tc);
      *(ushort4*)(base)        = hi;
      *(ushort4*)(base + 1024) = hi;
      *(ushort4*)(base + 2048) = lo;
    }
  }
}

// =====================================================================
// Router pass 1: 3 segment GEMMs (hi@hi, lo@hi, hi@lo), each 8192x128xK=1024,
// m97 structure. grid (64, 3). Writes rhpart[seg][tok][128] f32.
// =====================================================================
__global__ __launch_bounds__(256) void router_part(
    const unsigned short* __restrict__ xhi, const unsigned short* __restrict__ xlo,
    const unsigned short* __restrict__ w3, float* __restrict__ rhpart) {
  __shared__ unsigned short At[128 * 64];   // 16 KB
  __shared__ unsigned short Bt[128 * 64];   // 16 KB
  const int tid = threadIdx.x;
  const int m0 = blockIdx.x * 128;
  const int seg = blockIdx.y;               // 0,1,2
  const unsigned short* Abase = (seg == 1) ? xlo : xhi;
  const int kcol0 = seg * 1024;             // w3 column base

  const unsigned short* asrc[4];
  const unsigned short* bsrc[4];
  unsigned loff[4];
#pragma unroll
  for (int l = 0; l < 4; l++) {
    const unsigned o = l * 4096u + (unsigned)tid * 16u;
    const unsigned p = swz(o);
    const int row = (int)(o >> 7);            // 0..127 (swizzle-invariant)
    const int kel = (int)((p & 127u) >> 1);   // 0..63
    loff[l] = o;
    asrc[l] = Abase + (size_t)(m0 + row) * 1024 + kel;
    bsrc[l] = w3 + (size_t)row * 3072 + kcol0 + kel;
  }

  f32x4 acc[4][4];
#pragma unroll
  for (int i = 0; i < 4; i++)
#pragma unroll
    for (int j = 0; j < 4; j++) acc[i][j] = {0.f, 0.f, 0.f, 0.f};

  const int lane = tid & 63;
  const int wave = tid >> 6;
  const int wm = (wave >> 1) * 64;
  const int wn = (wave & 1) * 64;
  const int fr = lane & 15;
  const int fc = lane >> 4;

  for (int t = 0; t < 16; ++t) {
    __syncthreads();                       // WAR: prior step's reads done
#pragma unroll
    for (int l = 0; l < 4; l++) {
      __builtin_amdgcn_global_load_lds((gconst_t*)(asrc[l] + t * 64),
                                       (lds_t*)((char*)At + loff[l]), 16, 0, 0);
      __builtin_amdgcn_global_load_lds((gconst_t*)(bsrc[l] + t * 64),
                                       (lds_t*)((char*)Bt + loff[l]), 16, 0, 0);
    }
    __syncthreads();                       // RAW: compiler drains vmcnt here
    bf16x8 af[2][4], bv[2][4];
#pragma unroll
    for (int ks = 0; ks < 2; ks++) {
#pragma unroll
      for (int m = 0; m < 4; m++) {
        const unsigned L = (unsigned)(wm + m * 16 + fr) * 128u + (unsigned)(ks * 64 + fc * 16);
        af[ks][m] = *(const bf16x8*)((const char*)At + swz(L));
      }
#pragma unroll
      for (int n = 0; n < 4; n++) {
        const unsigned L = (unsigned)(wn + n * 16 + fr) * 128u + (unsigned)(ks * 64 + fc * 16);
        bv[ks][n] = *(const bf16x8*)((const char*)Bt + swz(L));
      }
    }
#pragma unroll
    for (int ks = 0; ks < 2; ks++)
#pragma unroll
      for (int m = 0; m < 4; m++)
#pragma unroll
        for (int n = 0; n < 4; n++)
          acc[m][n] = __builtin_amdgcn_mfma_f32_16x16x32_bf16(af[ks][m], bv[ks][n], acc[m][n], 0, 0, 0);
  }

  // write partials: C/D layout col=lane&15, row=(lane>>4)*4+reg
  const int crow = (lane >> 4) * 4;
  const int ccol = lane & 15;
  float* outp = rhpart + (size_t)seg * BATCH * 128;
#pragma unroll
  for (int mi = 0; mi < 4; mi++) {
#pragma unroll
    for (int r = 0; r < 4; r++) {
      const int tok = m0 + wm + mi * 16 + crow + r;
#pragma unroll
      for (int ni = 0; ni < 4; ni++)
        outp[(size_t)tok * 128 + (wn + ni * 16 + ccol)] = acc[mi][ni][r];
    }
  }
}

// =====================================================================
// Router pass 2: rh = relu(sum of 3 partials + b1); logits = rh@rw2 + b2
// (j ascending); argmax; atomic bucket. 64 blocks x 128 tokens.
// =====================================================================
__global__ __launch_bounds__(256) void router_finish(
    const float* __restrict__ rhpart, const float* __restrict__ rb1,
    const float* __restrict__ rw2, const float* __restrict__ rb2,
    int* __restrict__ counts, int* __restrict__ toklist) {
  __shared__ float rh[128 * 132];
  __shared__ float lg[128 * 3];
  const int tid = threadIdx.x;
  const int t0 = blockIdx.x * 128;
  constexpr size_t SEG = (size_t)BATCH * 128;

  for (int i = tid; i < 128 * 32; i += 256) {
    const int tok = i >> 5;
    const int c4 = (i & 31) * 4;
    const size_t base = (size_t)(t0 + tok) * 128 + c4;
    const float4 a = *(const float4*)(rhpart + base);
    const float4 b = *(const float4*)(rhpart + SEG + base);
    const float4 c = *(const float4*)(rhpart + 2 * SEG + base);
    const float4 bb = *(const float4*)(rb1 + c4);
    rh[tok * 132 + c4 + 0] = fmaxf(a.x + b.x + c.x + bb.x, 0.f);
    rh[tok * 132 + c4 + 1] = fmaxf(a.y + b.y + c.y + bb.y, 0.f);
    rh[tok * 132 + c4 + 2] = fmaxf(a.z + b.z + c.z + bb.z, 0.f);
    rh[tok * 132 + c4 + 3] = fmaxf(a.w + b.w + c.w + bb.w, 0.f);
  }
  __syncthreads();
#pragma unroll
  for (int pass = 0; pass < 2; ++pass) {
    const int t = tid + pass * 256;
    if (t < 384) {
      const int tok = t / 3, e = t - tok * 3;
      float s = rb2[e];
#pragma unroll 4
      for (int j = 0; j < 128; ++j) s = fmaf(rh[tok * 132 + j], rw2[j * 3 + e], s);
      lg[tok * 3 + e] = s;
    }
  }
  __syncthreads();
  if (tid < 128) {
    const float l0 = lg[tid * 3], l1 = lg[tid * 3 + 1], l2 = lg[tid * 3 + 2];
    int sel = 0; float m = l0;
    if (l1 > m) { m = l1; sel = 1; }
    if (l2 > m) { m = l2; sel = 2; }
    const int slot = atomicAdd(&counts[sel], 1);
    toklist[sel * BATCH + slot] = t0 + tid;
  }
}

// =====================================================================
// prep2: weight transpose+cvt only.
// =====================================================================
__global__ __launch_bounds__(256) void prep2_kernel(
    const float* __restrict__ ew1, const float* __restrict__ ew2,
    unsigned short* __restrict__ w1t, unsigned short* __restrict__ w2t) {
  __shared__ float tile[64][65];
  const int b = blockIdx.x;
  const int tid = threadIdx.x;

  const float* src; unsigned short* dst; int R, C, r0, c0;
  if (b < 3072) {
    const int e = b / 1024, w = b % 1024;
    src = ew1 + (size_t)e * 1024 * 4096; dst = w1t + (size_t)e * 4096 * 1024;
    R = 1024; C = 4096; r0 = (w & 15) * 64; c0 = (w >> 4) * 64;
  } else {
    const int bb = b - 3072, e = bb / 1024, w = bb % 1024;
    src = ew2 + (size_t)e * 4096 * 1024; dst = w2t + (size_t)e * 1024 * 4096;
    R = 4096; C = 1024; r0 = (w & 63) * 64; c0 = (w >> 6) * 64;
  }
  const int tr = tid >> 4;
  const int tc = (tid & 15) << 2;
#pragma unroll
  for (int i = 0; i < 4; i++) {
    const int r = tr + i * 16;
    const float4 v = *(const float4*)(src + (size_t)(r0 + r) * C + (c0 + tc));
    tile[r][tc + 0] = v.x; tile[r][tc + 1] = v.y; tile[r][tc + 2] = v.z; tile[r][tc + 3] = v.w;
  }
  __syncthreads();
#pragma unroll
  for (int i = 0; i < 4; i++) {
    const int c = tr + i * 16;
    ushort4 o;
    o.x = f2bf(tile[tc + 0][c]);
    o.y = f2bf(tile[tc + 1][c]);
    o.z = f2bf(tile[tc + 2][c]);
    o.w = f2bf(tile[tc + 3][c]);
    *(ushort4*)(dst + (size_t)(c0 + c) * R + (r0 + tc)) = o;
  }
}

// =====================================================================
// Grouped bf16 GEMM — EXACT round-4/5/6 structure (best measured: ~80-100
// us/dispatch by round-total bookkeeping). BM=128, BN=256, BK=32, 8 waves
// (2M x 4N), 64x64/wave. NBUF=3 counted-vmcnt pipeline: one s_barrier per
// K-step, steady vmcnt(3), lgkmcnt(0)+sched_barrier before MFMA, STAGE(t+2)
// issued AFTER the MFMA cluster.
// MODE 0: K=1024, A = xb gathered via toklist, relu(+b1) -> H bf16 grouped.
// MODE 1: K=4096, A = H grouped, +b2 -> scatter f32 rows of d_out.
// =====================================================================
template <int MODE>
__global__ __launch_bounds__(512, 2) void moe_gemm(
    const unsigned short* __restrict__ Abase, const unsigned short* __restrict__ Ball,
    const float* __restrict__ biasAll, unsigned short* __restrict__ Hout,
    float* __restrict__ Yout, const int* __restrict__ toklist, const int* __restrict__ counts,
    float* __restrict__ tail) {
  constexpr int N  = (MODE == 0) ? HID : OUT_DIM;
  constexpr int K  = (MODE == 0) ? IN_DIM : HID;
  constexpr int NT = K / 32;

  const int tid = threadIdx.x;
  if (MODE == 0 && blockIdx.x == 0 && blockIdx.y == 0 && tid < NE)
    tail[tid] = (float)counts[tid];

  const int c0 = counts[0], c1 = counts[1], c2 = counts[2];
  const int mb0 = (c0 + 127) >> 7, mb1 = (c1 + 127) >> 7, mb2 = (c2 + 127) >> 7;
  const int bx = blockIdx.x;
  int e, mblk;
  if (bx < mb0) { e = 0; mblk = bx; }
  else if (bx < mb0 + mb1) { e = 1; mblk = bx - mb0; }
  else if (bx < mb0 + mb1 + mb2) { e = 2; mblk = bx - mb0 - mb1; }
  else return;
  const int cnt = (e == 0) ? c0 : (e == 1) ? c1 : c2;
  const int m0 = mblk * 128;
  const int n0 = blockIdx.y * 256;
  const int off_e = (e > 0 ? c0 : 0) + (e > 1 ? c1 : 0);
  const unsigned short* Bmat = Ball + (size_t)e * ((size_t)N * K);
  const float* bias = biasAll + (size_t)e * N;

  __shared__ unsigned short Ab[3][128 * 32];   // 8 KB per buf
  __shared__ unsigned short Bb[3][256 * 32];   // 16 KB per buf   (total 72 KB)

  // staging: LDS dest linear o; global source pre-swizzled p so readers'
  // XOR(addr, (row&3)<<4) recovers logical (row, kslot). Rows are 64 B.
  const unsigned short* asrc;
  const unsigned short* bsrc[2];
  unsigned aoff, boff[2];
  {
    const unsigned o = (unsigned)tid * 16u;
    const unsigned p = o ^ (((o >> 6) & 3u) << 4);
    const int row = (int)(o >> 6);
    const int kel = (int)((p & 63u) >> 1);
    aoff = o;
    int slot = m0 + row; if (slot > cnt - 1) slot = cnt - 1;
    const size_t arow = (MODE == 0) ? (size_t)toklist[e * BATCH + slot]
                                    : (size_t)(off_e + slot);
    asrc = Abase + arow * K + kel;
  }
#pragma unroll
  for (int l = 0; l < 2; l++) {
    const unsigned o = l * 8192u + (unsigned)tid * 16u;
    const unsigned p = o ^ (((o >> 6) & 3u) << 4);
    const int row = (int)(o >> 6);
    const int kel = (int)((p & 63u) >> 1);
    boff[l] = o;
    bsrc[l] = Bmat + (size_t)(n0 + row) * K + kel;
  }

  f32x4 acc[4][4];
#pragma unroll
  for (int i = 0; i < 4; i++)
#pragma unroll
    for (int j = 0; j < 4; j++) acc[i][j] = {0.f, 0.f, 0.f, 0.f};

  const int lane = tid & 63;
  const int wave = tid >> 6;
  const int wm = (wave >> 2) * 64;
  const int wn = (wave & 3) * 64;
  const int fr = lane & 15;
  const int fc = lane >> 4;

  auto STAGE = [&](int buf, int kofs) {
    __builtin_amdgcn_global_load_lds((gconst_t*)(asrc + kofs),
                                     (lds_t*)((char*)&Ab[buf][0] + aoff), 16, 0, 0);
#pragma unroll
    for (int l = 0; l < 2; l++)
      __builtin_amdgcn_global_load_lds((gconst_t*)(bsrc[l] + kofs),
                                       (lds_t*)((char*)&Bb[buf][0] + boff[l]), 16, 0, 0);
  };

  STAGE(0, 0);
  STAGE(1, 32);

  int cur = 0;
  for (int t = 0; t < NT; ++t) {
    if (t + 1 < NT) asm volatile("s_waitcnt vmcnt(3)" ::: "memory");
    else            asm volatile("s_waitcnt vmcnt(0)" ::: "memory");
    __builtin_amdgcn_sched_barrier(0);
    __builtin_amdgcn_s_barrier();          // all waves' stage-t landed
    __builtin_amdgcn_sched_barrier(0);
    bf16x8 af[4], bv[4];
#pragma unroll
    for (int m = 0; m < 4; m++) {
      const unsigned row = (unsigned)(wm + m * 16 + fr);
      const unsigned addr = ((row << 6) + (unsigned)(fc << 4)) ^ ((row & 3u) << 4);
      af[m] = *(const bf16x8*)((const char*)&Ab[cur][0] + addr);
    }
#pragma unroll
    for (int n = 0; n < 4; n++) {
      const unsigned row = (unsigned)(wn + n * 16 + fr);
      const unsigned addr = ((row << 6) + (unsigned)(fc << 4)) ^ ((row & 3u) << 4);
      bv[n] = *(const bf16x8*)((const char*)&Bb[cur][0] + addr);
    }
    asm volatile("s_waitcnt lgkmcnt(0)" ::: "memory");
    __builtin_amdgcn_sched_barrier(0);     // rule #18: pin MFMA after the wait
    __builtin_amdgcn_s_setprio(1);
#pragma unroll
    for (int m = 0; m < 4; m++)
#pragma unroll
      for (int n = 0; n < 4; n++)
        acc[m][n] = __builtin_amdgcn_mfma_f32_16x16x32_bf16(af[m], bv[n], acc[m][n], 0, 0, 0);
    __builtin_amdgcn_s_setprio(0);
    if (t + 2 < NT) {
      const int nb = (cur + 2 >= 3) ? cur - 1 : cur + 2;
      STAGE(nb, (t + 2) * 32);
    }
    cur = (cur + 1 == 3) ? 0 : cur + 1;
  }

  // epilogue: C/D layout col=lane&15, row=(lane>>4)*4+reg  [HW-verified m89/m91]
  const int crow = (lane >> 4) * 4;
  const int ccol = lane & 15;
#pragma unroll
  for (int mi = 0; mi < 4; mi++) {
#pragma unroll
    for (int r = 0; r < 4; r++) {
      const int slot = m0 + wm + mi * 16 + crow + r;
      if (slot >= cnt) continue;
      if (MODE == 0) {
        unsigned short* hrow = Hout + (size_t)(off_e + slot) * HID;
#pragma unroll
        for (int ni = 0; ni < 4; ni++) {
          const int n = n0 + wn + ni * 16 + ccol;
          const float v = acc[mi][ni][r] + bias[n];
          hrow[n] = f2bf(fmaxf(v, 0.f));
        }
      } else {
        const int tok = toklist[e * BATCH + slot];
        float* yrow = Yout + (size_t)tok * OUT_DIM;
#pragma unroll
        for (int ni = 0; ni < 4; ni++) {
          const int n = n0 + wn + ni * 16 + ccol;
          yrow[n] = acc[mi][ni][r] + bias[n];
        }
      }
    }
  }
}

extern "C" void kernel_launch(void* const* d_in, const int* in_sizes, int n_in,
                              void* d_out, int out_size, void* d_ws, size_t ws_size,
                              hipStream_t stream) {
  const float* x   = (const float*)d_in[0];
  const float* rw1 = (const float*)d_in[1];
  const float* rb1 = (const float*)d_in[2];
  const float* rw2 = (const float*)d_in[3];
  const float* rb2 = (const float*)d_in[4];
  const float* ew1 = (const float*)d_in[5];
  const float* eb1 = (const float*)d_in[6];
  const float* ew2 = (const float*)d_in[7];
  const float* eb2 = (const float*)d_in[8];
  float* out = (float*)d_out;

  char* ws = (char*)d_ws;
  unsigned short* xb  = (unsigned short*)(ws + XBF_OFF);
  unsigned short* w1t = (unsigned short*)(ws + W1T_OFF);
  unsigned short* w2t = (unsigned short*)(ws + W2T_OFF);
  unsigned short* h   = (unsigned short*)(ws + H_OFF);
  unsigned short* xlo = (unsigned short*)(ws + XLO_OFF);   // aliases H (see layout)
  float* rhpart = (float*)(ws + RHP_OFF);                  // aliases H (see layout)
  int* counts  = (int*)(ws + META_OFF);
  int* toklist = counts + 16;
  unsigned short* w3 = (unsigned short*)(ws + W3_OFF);
  float* tail = out + (size_t)BATCH * OUT_DIM;

  hipMemsetAsync(counts, 0, 64, stream);
  prepA_kernel<<<544, 256, 0, stream>>>(x, rw1, xb, xlo, w3);
  router_part<<<dim3(64, 3), 256, 0, stream>>>(xb, xlo, w3, rhpart);
  router_finish<<<64, 256, 0, stream>>>(rhpart, rb1, rw2, rb2, counts, toklist);
  prep2_kernel<<<6144, 256, 0, stream>>>(ew1, ew2, w1t, w2t);
  moe_gemm<0><<<dim3(66, 16), 512, 0, stream>>>(xb, w1t, eb1, h, nullptr, toklist, counts, tail);
  moe_gemm<1><<<dim3(66, 4), 512, 0, stream>>>(h, w2t, eb2, nullptr, out, toklist, counts, tail);
}